// Round 11
// baseline (479.669 us; speedup 1.0000x reference)
//
#include <hip/hip_runtime.h>

typedef __attribute__((ext_vector_type(8))) short short8;
typedef __attribute__((ext_vector_type(4))) float f32x4;

#define N_ROWS   65536
#define DIM      64
#define K_CODES  1024
#define TOTAL_ELEMS 4194304   // N_ROWS * DIM
#define THETA    1e-3f        // cert margin (proven passing r3-r10)
#define ROWS_PB  64           // rows per k_assign block (r5-proven shape)

// ---------------- ws layout (4-byte units) ----------------
// [0      , 1024 )   norms ||e_k||^2 (float)
// [1024   , 66560)   indices (int)
// [66560  , 67584)   counts (int)
// [67584  , 71680)   loss partials (float, 4096)
// [71680  , 137216)  cbT[k][d] f32
// [137216 , 169984)  cb_hi[k][d] bf16 of (-2*e)  (ushort)
// [169984 , 202752)  cb_lo[k][d] bf16 residual   (ushort)
// [202752 , 202754)  sync: [0]=flag counter, [1]=quant done counter (int)
// [202754 , 268290)  flag list (int)

__device__ __forceinline__ unsigned short f2bf(float f) {
    union { float f; unsigned int u; } c; c.f = f;
    unsigned int u = c.u;
    return (unsigned short)((u + 0x7fffu + ((u >> 16) & 1u)) >> 16);  // RNE
}
__device__ __forceinline__ float bf2f(unsigned short b) {
    union { unsigned int u; float f; } c; c.u = ((unsigned int)b) << 16;
    return c.f;
}
__device__ __forceinline__ f32x4 MFMA(short8 a, short8 b, f32x4 c) {
    return __builtin_amdgcn_mfma_f32_16x16x32_bf16(a, b, c, 0, 0, 0);
}

// norms, cbT, bf16 split of -2*e; zero counts + sync counters.
__global__ __launch_bounds__(128) void k_prep(const float* __restrict__ cb,
                                              float* __restrict__ norms,
                                              int* __restrict__ counts,
                                              float* __restrict__ cbT,
                                              unsigned short* __restrict__ cb_hi,
                                              unsigned short* __restrict__ cb_lo,
                                              int* __restrict__ sync) {
    int k = blockIdx.x * 128 + threadIdx.x;   // 8 blocks -> 1024
    float v0 = cb[k];
    float s = __fmul_rn(v0, v0);
    cbT[k * DIM] = v0;
    {
        float t = -2.0f * v0;                 // exact
        unsigned short hb = f2bf(t);
        cb_hi[k * DIM] = hb;
        cb_lo[k * DIM] = f2bf(t - bf2f(hb));
    }
#pragma unroll 4
    for (int d = 1; d < DIM; ++d) {
        float v = cb[d * K_CODES + k];
        s = __fadd_rn(s, __fmul_rn(v, v));
        cbT[k * DIM + d] = v;
        float t = -2.0f * v;
        unsigned short hb = f2bf(t);
        cb_hi[k * DIM + d] = hb;
        cb_lo[k * DIM + d] = f2bf(t - bf2f(hb));
    }
    norms[k] = s;
    counts[k] = 0;
    if (k == 0) { sync[0] = 0; sync[1] = 0; }
}

// Phase 1: split-bf16 MFMA distance argmin with certificate.
// VERBATIM r5 kernel (64 us, VGPR 100, zero spill) — do not touch the inner loop.
__global__ __launch_bounds__(256, 2) void k_assign(const float* __restrict__ x,
                                                   const float* __restrict__ norms,
                                                   const unsigned short* __restrict__ cb_hi,
                                                   const unsigned short* __restrict__ cb_lo,
                                                   int* __restrict__ idx_out,
                                                   int* __restrict__ flagcnt,
                                                   int* __restrict__ flaglist) {
    __shared__ __align__(16) unsigned short xs_hi[64 * 64];  // XOR-swizzled
    __shared__ __align__(16) unsigned short xs_lo[64 * 64];
    __shared__ float xxs[64];
    __shared__ float mv1[4][64];
    __shared__ float mv2[4][64];
    __shared__ int   mk1[4][64];

    const int tid = threadIdx.x;
    const int r0 = blockIdx.x * 64;
    const int wave = tid >> 6, lane = tid & 63;
    const int lr = lane & 15, lg = lane >> 4;

#pragma unroll
    for (int i = 0; i < 2; ++i) {
        int c = i * 256 + tid;
        int row = c >> 3, ch = c & 7;
        const float4* src = reinterpret_cast<const float4*>(x + (size_t)(r0 + row) * DIM + ch * 8);
        float4 f0 = src[0], f1 = src[1];
        float f[8] = {f0.x, f0.y, f0.z, f0.w, f1.x, f1.y, f1.z, f1.w};
        union { short8 v; unsigned short u[8]; } h, l;
#pragma unroll
        for (int j = 0; j < 8; ++j) {
            unsigned short hb = f2bf(f[j]);
            h.u[j] = hb;
            l.u[j] = f2bf(f[j] - bf2f(hb));
        }
        int eo = row * 64 + ((((ch * 16) ^ ((row & 7) << 4))) >> 1);
        *reinterpret_cast<short8*>(&xs_hi[eo]) = h.v;
        *reinterpret_cast<short8*>(&xs_lo[eo]) = l.v;
    }
    if (lane < 16) {
        int row = wave * 16 + lane;
        const float* xr = x + (size_t)(r0 + row) * DIM;
        float r[8];
#pragma unroll
        for (int j = 0; j < 8; ++j) { float v = xr[j]; r[j] = __fmul_rn(v, v); }
#pragma unroll
        for (int m = 1; m < 8; ++m)
#pragma unroll
            for (int j = 0; j < 8; ++j) { float v = xr[8 * m + j]; r[j] = __fadd_rn(r[j], __fmul_rn(v, v)); }
        float t01 = __fadd_rn(r[0], r[1]), t23 = __fadd_rn(r[2], r[3]);
        float t45 = __fadd_rn(r[4], r[5]), t67 = __fadd_rn(r[6], r[7]);
        xxs[row] = __fadd_rn(__fadd_rn(t01, t23), __fadd_rn(t45, t67));
    }
    __syncthreads();

    short8 a_hi[4][2], a_lo[4][2];
#pragma unroll
    for (int rt = 0; rt < 4; ++rt)
#pragma unroll
        for (int kh = 0; kh < 2; ++kh) {
            int row = rt * 16 + lr;
            int bo = (kh * 64 + lg * 16) ^ ((row & 7) << 4);
            int eo = row * 64 + (bo >> 1);
            a_hi[rt][kh] = *reinterpret_cast<const short8*>(&xs_hi[eo]);
            a_lo[rt][kh] = *reinterpret_cast<const short8*>(&xs_lo[eo]);
        }
    float xxv[16];
#pragma unroll
    for (int rt = 0; rt < 4; ++rt)
#pragma unroll
        for (int r = 0; r < 4; ++r) xxv[rt * 4 + r] = xxs[rt * 16 + lg * 4 + r];

    float v1[16], v2[16]; int k1[16];
#pragma unroll
    for (int i = 0; i < 16; ++i) { v1[i] = 3.4e38f; v2[i] = 3.4e38f; k1[i] = 0; }

    const short8* ph = reinterpret_cast<const short8*>(cb_hi) + (size_t)(wave * 256 + lr) * 8;
    const short8* pl = reinterpret_cast<const short8*>(cb_lo) + (size_t)(wave * 256 + lr) * 8;
    const float*  pe = norms + wave * 256 + lr;

    short8 nh0 = ph[lg], nh1 = ph[4 + lg];
    short8 nl0 = pl[lg], nl1 = pl[4 + lg];
    float  nee = *pe;

    for (int ct = 0; ct < 16; ++ct) {
        short8 h0 = nh0, h1 = nh1, l0 = nl0, l1 = nl1;
        float ee = nee;
        if (ct < 15) {
            ph += 128; pl += 128; pe += 16;
            nh0 = ph[lg]; nh1 = ph[4 + lg];
            nl0 = pl[lg]; nl1 = pl[4 + lg];
            nee = *pe;
        }
        int code = wave * 256 + ct * 16 + lr;

#pragma unroll
        for (int rt = 0; rt < 4; ++rt) {
            f32x4 acc;
            acc[0] = __fadd_rn(xxv[rt * 4 + 0], ee);
            acc[1] = __fadd_rn(xxv[rt * 4 + 1], ee);
            acc[2] = __fadd_rn(xxv[rt * 4 + 2], ee);
            acc[3] = __fadd_rn(xxv[rt * 4 + 3], ee);
            acc = MFMA(a_hi[rt][0], h0, acc);
            acc = MFMA(a_hi[rt][1], h1, acc);
            acc = MFMA(a_hi[rt][0], l0, acc);
            acc = MFMA(a_hi[rt][1], l1, acc);
            acc = MFMA(a_lo[rt][0], h0, acc);
            acc = MFMA(a_lo[rt][1], h1, acc);
#pragma unroll
            for (int r = 0; r < 4; ++r) {
                int i = rt * 4 + r;
                float d = acc[r];
                bool lt = d < v1[i];
                v2[i] = lt ? v1[i] : fminf(v2[i], d);
                k1[i] = lt ? code : k1[i];
                v1[i] = lt ? d : v1[i];
            }
        }
    }

#pragma unroll
    for (int i = 0; i < 16; ++i) {
        float a1 = v1[i], a2 = v2[i]; int ak = k1[i];
#pragma unroll
        for (int off = 1; off <= 8; off <<= 1) {
            float o1 = __shfl_xor(a1, off);
            float o2 = __shfl_xor(a2, off);
            int   ok = __shfl_xor(ak, off);
            float n2 = fminf(fmaxf(a1, o1), fminf(a2, o2));
            if (o1 < a1 || (o1 == a1 && ok < ak)) { a1 = o1; ak = ok; }
            a2 = n2;
        }
        if (lr == 0) {
            int row = (i >> 2) * 16 + lg * 4 + (i & 3);
            mv1[wave][row] = a1; mv2[wave][row] = a2; mk1[wave][row] = ak;
        }
    }
    __syncthreads();

    if (tid < 64) {
        float V1 = mv1[0][tid], V2 = mv2[0][tid]; int K1 = mk1[0][tid];
#pragma unroll
        for (int w = 1; w < 4; ++w) {
            float a1 = mv1[w][tid], a2 = mv2[w][tid]; int ak = mk1[w][tid];
            float n2 = fminf(fmaxf(V1, a1), fminf(V2, a2));
            if (a1 < V1) { V1 = a1; K1 = ak; }
            V2 = n2;
        }
        int rg = r0 + tid;
        idx_out[rg] = K1;                      // placeholder if flagged
        if (V2 - V1 <= THETA) {
            int p = atomicAdd(flagcnt, 1);     // set deterministic; order irrelevant
            flaglist[p] = rg;
        }
    }
}

// Phase 2: exact re-rank. 8 flagged rows per group, coalesced d-major
// codebook reads amortized over the 8 rows; grid-stride over groups.
__global__ __launch_bounds__(256) void k_exact(const float* __restrict__ x,
                                               const float* __restrict__ cb,
                                               const float* __restrict__ norms,
                                               const int* __restrict__ flagcnt,
                                               const int* __restrict__ flaglist,
                                               int* __restrict__ idx) {
    __shared__ __align__(16) float xrow[8][64];
    __shared__ float xxs[8];
    __shared__ int rlist[8];
    __shared__ float lv[8][4];
    __shared__ int   lk[8][4];

    const int tid = threadIdx.x;
    const int lane = tid & 63, wv = tid >> 6;
    const int cnt = flagcnt[0];
    const int ngroups = (cnt + 7) >> 3;

    for (int g = blockIdx.x; g < ngroups; g += gridDim.x) {
        const int base = g * 8;
        const int rem = min(8, cnt - base);
        __syncthreads();                        // protect LDS reuse across groups
        if (tid < 8)
            rlist[tid] = flaglist[base + ((tid < rem) ? tid : 0)];
        __syncthreads();
#pragma unroll
        for (int i = 0; i < 2; ++i) {           // 512 elements
            int e = i * 256 + tid;
            int r = e >> 6, d = e & 63;
            xrow[r][d] = x[(size_t)rlist[r] * DIM + d];
        }
        __syncthreads();
        if (tid < 8) {                          // numpy pairwise ||x||^2
            float rr[8];
#pragma unroll
            for (int j = 0; j < 8; ++j) { float v = xrow[tid][j]; rr[j] = __fmul_rn(v, v); }
#pragma unroll
            for (int m = 1; m < 8; ++m)
#pragma unroll
                for (int j = 0; j < 8; ++j) { float v = xrow[tid][8 * m + j]; rr[j] = __fadd_rn(rr[j], __fmul_rn(v, v)); }
            float t01 = __fadd_rn(rr[0], rr[1]), t23 = __fadd_rn(rr[2], rr[3]);
            float t45 = __fadd_rn(rr[4], rr[5]), t67 = __fadd_rn(rr[6], rr[7]);
            xxs[tid] = __fadd_rn(__fadd_rn(t01, t23), __fadd_rn(t45, t67));
        }
        __syncthreads();

        double acc[8][4];
#pragma unroll
        for (int r = 0; r < 8; ++r)
#pragma unroll
            for (int j = 0; j < 4; ++j) acc[r][j] = 0.0;

        for (int dc = 0; dc < DIM; dc += 4) {
            float4 xv[8];
#pragma unroll
            for (int r = 0; r < 8; ++r)
                xv[r] = *reinterpret_cast<const float4*>(&xrow[r][dc]);   // LDS broadcast
            float c[4][4];
#pragma unroll
            for (int dd = 0; dd < 4; ++dd)
#pragma unroll
                for (int j = 0; j < 4; ++j)
                    c[j][dd] = cb[(size_t)(dc + dd) * K_CODES + j * 256 + tid];  // coalesced
#pragma unroll
            for (int j = 0; j < 4; ++j)
#pragma unroll
                for (int r = 0; r < 8; ++r) {
                    acc[r][j] += (double)xv[r].x * (double)c[j][0];
                    acc[r][j] += (double)xv[r].y * (double)c[j][1];
                    acc[r][j] += (double)xv[r].z * (double)c[j][2];
                    acc[r][j] += (double)xv[r].w * (double)c[j][3];
                }
        }

#pragma unroll
        for (int r = 0; r < 8; ++r) {
            float xx = xxs[r];
            float bv = 3.4e38f; int bk = 0x7fffffff;
#pragma unroll
            for (int j = 0; j < 4; ++j) {       // ascending k per thread
                int k = j * 256 + tid;
                float m = (float)acc[r][j];
                float dist = __fsub_rn(__fadd_rn(xx, norms[k]), __fmul_rn(2.0f, m));
                if (dist < bv) { bv = dist; bk = k; }
            }
#pragma unroll
            for (int off = 1; off <= 32; off <<= 1) {
                float ov = __shfl_xor(bv, off); int ok = __shfl_xor(bk, off);
                if (ov < bv || (ov == bv && ok < bk)) { bv = ov; bk = ok; }
            }
            if (lane == 0) { lv[r][wv] = bv; lk[r][wv] = bk; }
        }
        __syncthreads();
        if (tid < rem) {
            float bv = lv[tid][0]; int bk = lk[tid][0];
#pragma unroll
            for (int w = 1; w < 4; ++w)
                if (lv[tid][w] < bv || (lv[tid][w] == bv && lk[tid][w] < bk)) { bv = lv[tid][w]; bk = lk[tid][w]; }
            idx[rlist[tid]] = bk;
        }
    }
}

// Gather + STE + loss partial + histogram + idxf; LAST finishing block also
// performs the final scalar reduction (deterministic: fixed-order arithmetic,
// independent of which block executes it).
__global__ __launch_bounds__(256) void k_quant(const float* __restrict__ x,
                                               const float* __restrict__ cbT,
                                               const int* __restrict__ idx,
                                               float* __restrict__ ste,
                                               float* __restrict__ partials,
                                               int* __restrict__ counts,
                                               float* __restrict__ idxf,
                                               int* __restrict__ done,
                                               float* __restrict__ out_scalars) {
    int t  = blockIdx.x * 256 + threadIdx.x;
    int e  = t << 2;
    int n  = e >> 6;
    int dc = e & 63;
    float4 xv = *reinterpret_cast<const float4*>(x + e);
    int k = idx[n];
    float4 qv = *reinterpret_cast<const float4*>(cbT + (size_t)k * DIM + dc);

    float4 sv;
    sv.x = xv.x + (qv.x - xv.x);
    sv.y = xv.y + (qv.y - xv.y);
    sv.z = xv.z + (qv.z - xv.z);
    sv.w = xv.w + (qv.w - xv.w);
    *reinterpret_cast<float4*>(ste + e) = sv;

    if (dc == 0) {
        atomicAdd(&counts[k], 1);
        idxf[n] = (float)k;
    }

    float dx = qv.x - xv.x, dy = qv.y - xv.y, dz = qv.z - xv.z, dw = qv.w - xv.w;
    float s = dx * dx + dy * dy + dz * dz + dw * dw;

#pragma unroll
    for (int off = 32; off >= 1; off >>= 1) s += __shfl_down(s, off);
    __shared__ float red[4];
    int wave = threadIdx.x >> 6, lane = threadIdx.x & 63;
    if (lane == 0) red[wave] = s;
    __syncthreads();
    if (threadIdx.x == 0)
        partials[blockIdx.x] = (red[0] + red[1]) + (red[2] + red[3]);

    // ---- last-block final reduction ----
    __shared__ int isLast;
    __threadfence();                            // publish partials/counts/idxf
    if (threadIdx.x == 0)
        isLast = (atomicAdd(done, 1) == 4095);
    __syncthreads();
    if (!isLast) return;
    __threadfence();                            // acquire all blocks' writes

    const int tid = threadIdx.x;
    float S = 0.f;
#pragma unroll
    for (int j = 0; j < 16; ++j) S += partials[tid + 256 * j];
    float T = 0.f;
#pragma unroll
    for (int j = 0; j < 4; ++j) {
        float c = (float)counts[tid + 256 * j];
        float p = c * (1.0f / 65536.0f);
        T += -p * logf(p + 1e-10f);
    }
#pragma unroll
    for (int off = 32; off >= 1; off >>= 1) {
        S += __shfl_down(S, off);
        T += __shfl_down(T, off);
    }
    __shared__ float fs[4], ft[4];
    if (lane == 0) { fs[wave] = S; ft[wave] = T; }
    __syncthreads();
    if (tid == 0) {
        float total = (fs[0] + fs[1]) + (fs[2] + fs[3]);
        float ent   = (ft[0] + ft[1]) + (ft[2] + ft[3]);
        float mean = total * (1.0f / (float)TOTAL_ELEMS);
        out_scalars[0] = expf(ent);      // perplexity
        out_scalars[1] = mean;           // codebook_loss
        out_scalars[2] = 0.25f * mean;   // commitment_loss
    }
}

extern "C" void kernel_launch(void* const* d_in, const int* in_sizes, int n_in,
                              void* d_out, int out_size, void* d_ws, size_t ws_size,
                              hipStream_t stream) {
    const float* x  = (const float*)d_in[0];
    const float* cb = (const float*)d_in[1];
    float* out = (float*)d_out;
    float* ws  = (float*)d_ws;

    float* norms    = ws;
    int*   idx      = (int*)(ws + 1024);
    int*   counts   = (int*)(ws + 66560);
    float* partials = ws + 67584;
    float* cbT      = ws + 71680;
    unsigned short* cb_hi = (unsigned short*)(ws + 137216);
    unsigned short* cb_lo = (unsigned short*)(ws + 169984);
    int*   sync     = (int*)(ws + 202752);      // [0]=flagcnt, [1]=done
    int*   flaglist = (int*)(ws + 202754);

    float* ste     = out;
    float* scalars = out + TOTAL_ELEMS;
    float* idxf    = out + TOTAL_ELEMS + 3;

    k_prep  <<<8,    128, 0, stream>>>(cb, norms, counts, cbT, cb_hi, cb_lo, sync);
    k_assign<<<1024, 256, 0, stream>>>(x, norms, cb_hi, cb_lo, idx, sync, flaglist);
    k_exact <<<1024, 256, 0, stream>>>(x, cb, norms, sync, flaglist, idx);
    k_quant <<<4096, 256, 0, stream>>>(x, cbT, idx, ste, partials, counts, idxf,
                                       sync + 1, scalars);
}

// Round 12
// 111.613 us; speedup vs baseline: 4.2976x; 4.2976x over previous
//
#include <hip/hip_runtime.h>

typedef __attribute__((ext_vector_type(8))) short short8;
typedef __attribute__((ext_vector_type(4))) float f32x4;

#define N_ROWS   65536
#define DIM      64
#define K_CODES  1024
#define TOTAL_ELEMS 4194304   // N_ROWS * DIM
#define THETA    1e-3f        // cert margin (proven passing r3-r11)
#define ROWS_PB  64           // rows per k_assign block (r5-proven shape)

// ---------------- ws layout (4-byte units) ----------------
// [0      , 1024 )   norms ||e_k||^2 (float)
// [1024   , 66560)   indices (int)
// [66560  , 67584)   counts (int)
// [67584  , 71680)   loss partials (float, 4096)
// [71680  , 137216)  cbT[k][d] f32
// [137216 , 169984)  cb_hi[k][d] bf16 of (-2*e)  (ushort)
// [169984 , 202752)  cb_lo[k][d] bf16 residual   (ushort)
// [202752]           flag counter (int)
// [202753 , 268289)  flag list (int)

__device__ __forceinline__ unsigned short f2bf(float f) {
    union { float f; unsigned int u; } c; c.f = f;
    unsigned int u = c.u;
    return (unsigned short)((u + 0x7fffu + ((u >> 16) & 1u)) >> 16);  // RNE
}
__device__ __forceinline__ float bf2f(unsigned short b) {
    union { unsigned int u; float f; } c; c.u = ((unsigned int)b) << 16;
    return c.f;
}
__device__ __forceinline__ f32x4 MFMA(short8 a, short8 b, f32x4 c) {
    return __builtin_amdgcn_mfma_f32_16x16x32_bf16(a, b, c, 0, 0, 0);
}

// norms (sequential order — k_exact's reference emulation depends on it),
// cbT, bf16 split of -2*e; zero counts + flagcnt.
// 16 blocks x 64 threads, one thread per code; all 64 loads unrolled so they
// fly concurrently (the old 8-block unroll-4 version was latency-bound).
__global__ __launch_bounds__(64) void k_prep(const float* __restrict__ cb,
                                             float* __restrict__ norms,
                                             int* __restrict__ counts,
                                             float* __restrict__ cbT,
                                             unsigned short* __restrict__ cb_hi,
                                             unsigned short* __restrict__ cb_lo,
                                             int* __restrict__ flagcnt) {
    int k = blockIdx.x * 64 + threadIdx.x;   // 16 blocks -> 1024
    float v[64];
#pragma unroll
    for (int d = 0; d < DIM; ++d) v[d] = cb[d * K_CODES + k];   // coalesced, all in flight
    float s = __fmul_rn(v[0], v[0]);
#pragma unroll
    for (int d = 1; d < DIM; ++d) s = __fadd_rn(s, __fmul_rn(v[d], v[d]));  // bit-identical order
    norms[k] = s;
#pragma unroll
    for (int d = 0; d < DIM; ++d) {
        cbT[k * DIM + d] = v[d];
        float t = -2.0f * v[d];               // exact
        unsigned short hb = f2bf(t);
        cb_hi[k * DIM + d] = hb;
        cb_lo[k * DIM + d] = f2bf(t - bf2f(hb));
    }
    counts[k] = 0;
    if (k == 0) flagcnt[0] = 0;
}

// Phase 1: split-bf16 MFMA distance argmin with certificate.
// VERBATIM r5 kernel (64 us, VGPR 100, zero spill). The inner loop sits at a
// register-allocator tipping point (r6-r10: any reformulation -> 97MB spill,
// +21 us). Do not touch.
__global__ __launch_bounds__(256, 2) void k_assign(const float* __restrict__ x,
                                                   const float* __restrict__ norms,
                                                   const unsigned short* __restrict__ cb_hi,
                                                   const unsigned short* __restrict__ cb_lo,
                                                   int* __restrict__ idx_out,
                                                   int* __restrict__ flagcnt,
                                                   int* __restrict__ flaglist) {
    __shared__ __align__(16) unsigned short xs_hi[64 * 64];  // XOR-swizzled
    __shared__ __align__(16) unsigned short xs_lo[64 * 64];
    __shared__ float xxs[64];
    __shared__ float mv1[4][64];
    __shared__ float mv2[4][64];
    __shared__ int   mk1[4][64];

    const int tid = threadIdx.x;
    const int r0 = blockIdx.x * 64;
    const int wave = tid >> 6, lane = tid & 63;
    const int lr = lane & 15, lg = lane >> 4;

#pragma unroll
    for (int i = 0; i < 2; ++i) {
        int c = i * 256 + tid;
        int row = c >> 3, ch = c & 7;
        const float4* src = reinterpret_cast<const float4*>(x + (size_t)(r0 + row) * DIM + ch * 8);
        float4 f0 = src[0], f1 = src[1];
        float f[8] = {f0.x, f0.y, f0.z, f0.w, f1.x, f1.y, f1.z, f1.w};
        union { short8 v; unsigned short u[8]; } h, l;
#pragma unroll
        for (int j = 0; j < 8; ++j) {
            unsigned short hb = f2bf(f[j]);
            h.u[j] = hb;
            l.u[j] = f2bf(f[j] - bf2f(hb));
        }
        int eo = row * 64 + ((((ch * 16) ^ ((row & 7) << 4))) >> 1);
        *reinterpret_cast<short8*>(&xs_hi[eo]) = h.v;
        *reinterpret_cast<short8*>(&xs_lo[eo]) = l.v;
    }
    if (lane < 16) {
        int row = wave * 16 + lane;
        const float* xr = x + (size_t)(r0 + row) * DIM;
        float r[8];
#pragma unroll
        for (int j = 0; j < 8; ++j) { float v = xr[j]; r[j] = __fmul_rn(v, v); }
#pragma unroll
        for (int m = 1; m < 8; ++m)
#pragma unroll
            for (int j = 0; j < 8; ++j) { float v = xr[8 * m + j]; r[j] = __fadd_rn(r[j], __fmul_rn(v, v)); }
        float t01 = __fadd_rn(r[0], r[1]), t23 = __fadd_rn(r[2], r[3]);
        float t45 = __fadd_rn(r[4], r[5]), t67 = __fadd_rn(r[6], r[7]);
        xxs[row] = __fadd_rn(__fadd_rn(t01, t23), __fadd_rn(t45, t67));
    }
    __syncthreads();

    short8 a_hi[4][2], a_lo[4][2];
#pragma unroll
    for (int rt = 0; rt < 4; ++rt)
#pragma unroll
        for (int kh = 0; kh < 2; ++kh) {
            int row = rt * 16 + lr;
            int bo = (kh * 64 + lg * 16) ^ ((row & 7) << 4);
            int eo = row * 64 + (bo >> 1);
            a_hi[rt][kh] = *reinterpret_cast<const short8*>(&xs_hi[eo]);
            a_lo[rt][kh] = *reinterpret_cast<const short8*>(&xs_lo[eo]);
        }
    float xxv[16];
#pragma unroll
    for (int rt = 0; rt < 4; ++rt)
#pragma unroll
        for (int r = 0; r < 4; ++r) xxv[rt * 4 + r] = xxs[rt * 16 + lg * 4 + r];

    float v1[16], v2[16]; int k1[16];
#pragma unroll
    for (int i = 0; i < 16; ++i) { v1[i] = 3.4e38f; v2[i] = 3.4e38f; k1[i] = 0; }

    const short8* ph = reinterpret_cast<const short8*>(cb_hi) + (size_t)(wave * 256 + lr) * 8;
    const short8* pl = reinterpret_cast<const short8*>(cb_lo) + (size_t)(wave * 256 + lr) * 8;
    const float*  pe = norms + wave * 256 + lr;

    short8 nh0 = ph[lg], nh1 = ph[4 + lg];
    short8 nl0 = pl[lg], nl1 = pl[4 + lg];
    float  nee = *pe;

    for (int ct = 0; ct < 16; ++ct) {
        short8 h0 = nh0, h1 = nh1, l0 = nl0, l1 = nl1;
        float ee = nee;
        if (ct < 15) {
            ph += 128; pl += 128; pe += 16;
            nh0 = ph[lg]; nh1 = ph[4 + lg];
            nl0 = pl[lg]; nl1 = pl[4 + lg];
            nee = *pe;
        }
        int code = wave * 256 + ct * 16 + lr;

#pragma unroll
        for (int rt = 0; rt < 4; ++rt) {
            f32x4 acc;
            acc[0] = __fadd_rn(xxv[rt * 4 + 0], ee);
            acc[1] = __fadd_rn(xxv[rt * 4 + 1], ee);
            acc[2] = __fadd_rn(xxv[rt * 4 + 2], ee);
            acc[3] = __fadd_rn(xxv[rt * 4 + 3], ee);
            acc = MFMA(a_hi[rt][0], h0, acc);
            acc = MFMA(a_hi[rt][1], h1, acc);
            acc = MFMA(a_hi[rt][0], l0, acc);
            acc = MFMA(a_hi[rt][1], l1, acc);
            acc = MFMA(a_lo[rt][0], h0, acc);
            acc = MFMA(a_lo[rt][1], h1, acc);
#pragma unroll
            for (int r = 0; r < 4; ++r) {
                int i = rt * 4 + r;
                float d = acc[r];
                bool lt = d < v1[i];
                v2[i] = lt ? v1[i] : fminf(v2[i], d);
                k1[i] = lt ? code : k1[i];
                v1[i] = lt ? d : v1[i];
            }
        }
    }

#pragma unroll
    for (int i = 0; i < 16; ++i) {
        float a1 = v1[i], a2 = v2[i]; int ak = k1[i];
#pragma unroll
        for (int off = 1; off <= 8; off <<= 1) {
            float o1 = __shfl_xor(a1, off);
            float o2 = __shfl_xor(a2, off);
            int   ok = __shfl_xor(ak, off);
            float n2 = fminf(fmaxf(a1, o1), fminf(a2, o2));
            if (o1 < a1 || (o1 == a1 && ok < ak)) { a1 = o1; ak = ok; }
            a2 = n2;
        }
        if (lr == 0) {
            int row = (i >> 2) * 16 + lg * 4 + (i & 3);
            mv1[wave][row] = a1; mv2[wave][row] = a2; mk1[wave][row] = ak;
        }
    }
    __syncthreads();

    if (tid < 64) {
        float V1 = mv1[0][tid], V2 = mv2[0][tid]; int K1 = mk1[0][tid];
#pragma unroll
        for (int w = 1; w < 4; ++w) {
            float a1 = mv1[w][tid], a2 = mv2[w][tid]; int ak = mk1[w][tid];
            float n2 = fminf(fmaxf(V1, a1), fminf(V2, a2));
            if (a1 < V1) { V1 = a1; K1 = ak; }
            V2 = n2;
        }
        int rg = r0 + tid;
        idx_out[rg] = K1;                      // placeholder if flagged
        if (V2 - V1 <= THETA) {
            int p = atomicAdd(flagcnt, 1);     // set deterministic; order irrelevant
            flaglist[p] = rg;
        }
    }
}

// Phase 2: exact re-rank. 8 flagged rows per group, coalesced d-major
// codebook reads amortized over the 8 rows; grid-stride over groups.
__global__ __launch_bounds__(256) void k_exact(const float* __restrict__ x,
                                               const float* __restrict__ cb,
                                               const float* __restrict__ norms,
                                               const int* __restrict__ flagcnt,
                                               const int* __restrict__ flaglist,
                                               int* __restrict__ idx) {
    __shared__ __align__(16) float xrow[8][64];
    __shared__ float xxs[8];
    __shared__ int rlist[8];
    __shared__ float lv[8][4];
    __shared__ int   lk[8][4];

    const int tid = threadIdx.x;
    const int lane = tid & 63, wv = tid >> 6;
    const int cnt = flagcnt[0];
    const int ngroups = (cnt + 7) >> 3;

    for (int g = blockIdx.x; g < ngroups; g += gridDim.x) {
        const int base = g * 8;
        const int rem = min(8, cnt - base);
        __syncthreads();                        // protect LDS reuse across groups
        if (tid < 8)
            rlist[tid] = flaglist[base + ((tid < rem) ? tid : 0)];
        __syncthreads();
#pragma unroll
        for (int i = 0; i < 2; ++i) {           // 512 elements
            int e = i * 256 + tid;
            int r = e >> 6, d = e & 63;
            xrow[r][d] = x[(size_t)rlist[r] * DIM + d];
        }
        __syncthreads();
        if (tid < 8) {                          // numpy pairwise ||x||^2
            float rr[8];
#pragma unroll
            for (int j = 0; j < 8; ++j) { float v = xrow[tid][j]; rr[j] = __fmul_rn(v, v); }
#pragma unroll
            for (int m = 1; m < 8; ++m)
#pragma unroll
                for (int j = 0; j < 8; ++j) { float v = xrow[tid][8 * m + j]; rr[j] = __fadd_rn(rr[j], __fmul_rn(v, v)); }
            float t01 = __fadd_rn(rr[0], rr[1]), t23 = __fadd_rn(rr[2], rr[3]);
            float t45 = __fadd_rn(rr[4], rr[5]), t67 = __fadd_rn(rr[6], rr[7]);
            xxs[tid] = __fadd_rn(__fadd_rn(t01, t23), __fadd_rn(t45, t67));
        }
        __syncthreads();

        double acc[8][4];
#pragma unroll
        for (int r = 0; r < 8; ++r)
#pragma unroll
            for (int j = 0; j < 4; ++j) acc[r][j] = 0.0;

        for (int dc = 0; dc < DIM; dc += 4) {
            float4 xv[8];
#pragma unroll
            for (int r = 0; r < 8; ++r)
                xv[r] = *reinterpret_cast<const float4*>(&xrow[r][dc]);   // LDS broadcast
            float c[4][4];
#pragma unroll
            for (int dd = 0; dd < 4; ++dd)
#pragma unroll
                for (int j = 0; j < 4; ++j)
                    c[j][dd] = cb[(size_t)(dc + dd) * K_CODES + j * 256 + tid];  // coalesced
#pragma unroll
            for (int j = 0; j < 4; ++j)
#pragma unroll
                for (int r = 0; r < 8; ++r) {
                    acc[r][j] += (double)xv[r].x * (double)c[j][0];
                    acc[r][j] += (double)xv[r].y * (double)c[j][1];
                    acc[r][j] += (double)xv[r].z * (double)c[j][2];
                    acc[r][j] += (double)xv[r].w * (double)c[j][3];
                }
        }

#pragma unroll
        for (int r = 0; r < 8; ++r) {
            float xx = xxs[r];
            float bv = 3.4e38f; int bk = 0x7fffffff;
#pragma unroll
            for (int j = 0; j < 4; ++j) {       // ascending k per thread
                int k = j * 256 + tid;
                float m = (float)acc[r][j];
                float dist = __fsub_rn(__fadd_rn(xx, norms[k]), __fmul_rn(2.0f, m));
                if (dist < bv) { bv = dist; bk = k; }
            }
#pragma unroll
            for (int off = 1; off <= 32; off <<= 1) {
                float ov = __shfl_xor(bv, off); int ok = __shfl_xor(bk, off);
                if (ov < bv || (ov == bv && ok < bk)) { bv = ov; bk = ok; }
            }
            if (lane == 0) { lv[r][wv] = bv; lk[r][wv] = bk; }
        }
        __syncthreads();
        if (tid < rem) {
            float bv = lv[tid][0]; int bk = lk[tid][0];
#pragma unroll
            for (int w = 1; w < 4; ++w)
                if (lv[tid][w] < bv || (lv[tid][w] == bv && lk[tid][w] < bk)) { bv = lv[tid][w]; bk = lk[tid][w]; }
            idx[rlist[tid]] = bk;
        }
    }
}

// Gather + STE + loss partial + fused histogram + idxf write.
__global__ __launch_bounds__(256) void k_quant(const float* __restrict__ x,
                                               const float* __restrict__ cbT,
                                               const int* __restrict__ idx,
                                               float* __restrict__ ste,
                                               float* __restrict__ partials,
                                               int* __restrict__ counts,
                                               float* __restrict__ idxf) {
    int t  = blockIdx.x * 256 + threadIdx.x;
    int e  = t << 2;
    int n  = e >> 6;
    int dc = e & 63;
    float4 xv = *reinterpret_cast<const float4*>(x + e);
    int k = idx[n];
    float4 qv = *reinterpret_cast<const float4*>(cbT + (size_t)k * DIM + dc);

    float4 sv;
    sv.x = xv.x + (qv.x - xv.x);
    sv.y = xv.y + (qv.y - xv.y);
    sv.z = xv.z + (qv.z - xv.z);
    sv.w = xv.w + (qv.w - xv.w);
    *reinterpret_cast<float4*>(ste + e) = sv;

    if (dc == 0) {
        atomicAdd(&counts[k], 1);
        idxf[n] = (float)k;
    }

    float dx = qv.x - xv.x, dy = qv.y - xv.y, dz = qv.z - xv.z, dw = qv.w - xv.w;
    float s = dx * dx + dy * dy + dz * dz + dw * dw;

#pragma unroll
    for (int off = 32; off >= 1; off >>= 1) s += __shfl_down(s, off);
    __shared__ float red[4];
    int wave = threadIdx.x >> 6, lane = threadIdx.x & 63;
    if (lane == 0) red[wave] = s;
    __syncthreads();
    if (threadIdx.x == 0)
        partials[blockIdx.x] = (red[0] + red[1]) + (red[2] + red[3]);
}

__global__ __launch_bounds__(1024) void k_final(const float* __restrict__ partials,
                                                const int* __restrict__ counts,
                                                float* __restrict__ out_scalars) {
    int tid = threadIdx.x;
    float s = 0.f;
    for (int i = tid; i < 4096; i += 1024) s += partials[i];
#pragma unroll
    for (int off = 32; off >= 1; off >>= 1) s += __shfl_down(s, off);
    __shared__ float wsum[16];
    int wave = tid >> 6, lane = tid & 63;
    if (lane == 0) wsum[wave] = s;

    float c = (float)counts[tid];
    float p = c * (1.0f / 65536.0f);
    float t = -p * logf(p + 1e-10f);
#pragma unroll
    for (int off = 32; off >= 1; off >>= 1) t += __shfl_down(t, off);
    __shared__ float esum[16];
    if (lane == 0) esum[wave] = t;
    __syncthreads();

    if (tid == 0) {
        float total = 0.f, ent = 0.f;
        for (int w = 0; w < 16; ++w) { total += wsum[w]; ent += esum[w]; }
        float mean = total * (1.0f / (float)TOTAL_ELEMS);
        out_scalars[0] = expf(ent);
        out_scalars[1] = mean;
        out_scalars[2] = 0.25f * mean;
    }
}

extern "C" void kernel_launch(void* const* d_in, const int* in_sizes, int n_in,
                              void* d_out, int out_size, void* d_ws, size_t ws_size,
                              hipStream_t stream) {
    const float* x  = (const float*)d_in[0];
    const float* cb = (const float*)d_in[1];
    float* out = (float*)d_out;
    float* ws  = (float*)d_ws;

    float* norms    = ws;
    int*   idx      = (int*)(ws + 1024);
    int*   counts   = (int*)(ws + 66560);
    float* partials = ws + 67584;
    float* cbT      = ws + 71680;
    unsigned short* cb_hi = (unsigned short*)(ws + 137216);
    unsigned short* cb_lo = (unsigned short*)(ws + 169984);
    int*   flagcnt  = (int*)(ws + 202752);
    int*   flaglist = (int*)(ws + 202753);

    float* ste     = out;
    float* scalars = out + TOTAL_ELEMS;
    float* idxf    = out + TOTAL_ELEMS + 3;

    k_prep  <<<16,    64, 0, stream>>>(cb, norms, counts, cbT, cb_hi, cb_lo, flagcnt);
    k_assign<<<1024, 256, 0, stream>>>(x, norms, cb_hi, cb_lo, idx, flagcnt, flaglist);
    k_exact <<<1024, 256, 0, stream>>>(x, cb, norms, flagcnt, flaglist, idx);
    k_quant <<<4096, 256, 0, stream>>>(x, cbT, idx, ste, partials, counts, idxf);
    k_final <<<1,   1024, 0, stream>>>(partials, counts, scalars);
}